// Round 7
// baseline (1410.654 us; speedup 1.0000x reference)
//
#include <hip/hip_runtime.h>
#include <math.h>

#define NL 12
#define GRID_BLOCKS 784
#define GRID_WAVES 3136   // GRID_BLOCKS * 4

typedef short v8s __attribute__((ext_vector_type(8)));
typedef float v4f __attribute__((ext_vector_type(4)));

struct PrepArgs {
  const float* in[40];
  void* out[40];
  int n[40];      // input element count
  int mode[40];   // 0 plain fq, 1 transposed fq, 2 conv int-bf16, 3 conv1 int-bf16
  int tc[40];     // mode1 minor dim
  int ci[40], kk[40], kp[40], co[40];   // mode2 geometry
};

struct NetParams {
  PrepArgs pa;
  const float* x;        // NCHW f32 input
  uint2* xc;             // NHWC4 input codes, 1 pixel = 4 ushorts = uint2
  const ushort* wq[NL];
  const float* sg[NL];
  const float* sb[NL];
  const float* fw1; const float* fb1; const float* fw2; const float* fb2;
  float* rawA; float* rawB; float* pool;
  float* slots; float* wslot;
  unsigned* bars;        // software grid-barrier counters (zeroed host-side)
  float* out;
};

// power-of-two scale: 2^ceil(log2(max(maxv,1e-8)/levels)); f32 ratio (matches
// JAX), double log2/ceil so ceil lands on the right side of integer boundaries.
__device__ inline float p2_scale_f(float maxv, float levels) {
  float r = __fdiv_rn(fmaxf(maxv, 1e-8f), levels);
  return (float)exp2(ceil(log2((double)r)));
}

__device__ inline float vload(const float* p) { return *(volatile const float*)p; }

// ---- software grid barrier ----
// Valid because all GRID_BLOCKS are co-resident: __launch_bounds__(256,4)
// caps VGPR so occupancy is 4 blocks/CU -> capacity 1024 >= 784, and the CP
// places every block immediately at kernel start. Release: __syncthreads
// drains each wave's stores to L2, thread-0's __threadfence() does the
// agent-scope L2 writeback; acquire: __threadfence() invalidates stale
// cached lines before any post-barrier load. Bounded poll: never hangs CI.
__device__ inline void gsync(unsigned* ctr) {
  __syncthreads();
  if (threadIdx.x == 0) {
    __threadfence();
    unsigned arrived = atomicAdd(ctr, 1u) + 1u;
    if (arrived < GRID_BLOCKS) {
      int tries = 0;
      while (atomicAdd(ctr, 0u) < GRID_BLOCKS && tries < (1 << 26)) {
        __builtin_amdgcn_s_sleep(8);
        tries++;
      }
    }
    __threadfence();
  }
  __syncthreads();
}

// blockDim 256. Result valid on thread 0. All threads must reach.
__device__ inline float block_reduce_max256(float v) {
  __shared__ float sm[4];
  #pragma unroll
  for (int off = 32; off; off >>= 1) v = fmaxf(v, __shfl_down(v, off));
  if ((threadIdx.x & 63) == 0) sm[threadIdx.x >> 6] = v;
  __syncthreads();
  if (threadIdx.x == 0) v = fmaxf(fmaxf(sm[0], sm[1]), fmaxf(sm[2], sm[3]));
  return v;
}

// v >= 0; non-negative float bits compare like unsigned. Monotone-growing slot
// makes the stale-read skip safe (any cached value was truly written).
__device__ inline void slot_max_update(float* slot, float v) {
  volatile unsigned int* su = (volatile unsigned int*)slot;
  unsigned int bits = __float_as_uint(v);
  if (bits > *su) atomicMax((unsigned int*)slot, bits);
}

// integer-valued float -> bf16 bits by truncation (exact for |v| <= 256)
__device__ inline ushort ibf16(float v) {
  return (ushort)(__float_as_uint(v) >> 16);
}

// ---- stage: weight prep (blocks 0..39) + input max (blocks 40..) ----
__device__ void prep_stage(const NetParams& P) {
  if (blockIdx.x >= 40) {
    const float4* x4 = (const float4*)P.x;
    const int nx4 = 16 * 3 * 224 * 224 / 4;
    float m = 0.f;
    for (int i = (blockIdx.x - 40) * 256 + threadIdx.x; i < nx4;
         i += (GRID_BLOCKS - 40) * 256) {
      float4 v = x4[i];
      m = fmaxf(fmaxf(fmaxf(m, v.x), fmaxf(v.y, v.z)), v.w);
    }
    float bm = block_reduce_max256(m);
    if (threadIdx.x == 0) slot_max_update(P.slots + 0, bm);
    return;
  }
  __shared__ float ssc;
  const int t = blockIdx.x;
  const float* in = P.pa.in[t];
  const int n = P.pa.n[t], mode = P.pa.mode[t];
  float m = 0.f;
  for (int i = threadIdx.x; i < n; i += 256) m = fmaxf(m, fabsf(in[i]));
  float bm = block_reduce_max256(m);
  if (threadIdx.x == 0) {
    ssc = p2_scale_f(bm, 127.0f);
    if (mode >= 2) P.wslot[t] = ssc;
  }
  __syncthreads();
  const float s = ssc;
  if (mode == 3) {           // conv1 weights: [32][64], k = tap*4 + ci
    ushort* o = (ushort*)P.pa.out[t];
    for (int i = threadIdx.x; i < 32 * 64; i += 256) {
      int co = i >> 6, k = i & 63, tap = k >> 2, ci = k & 3;
      ushort v = 0;
      if (tap < 9 && ci < 3) {
        float q = rintf(__fdiv_rn(in[(co * 3 + ci) * 9 + tap], s));
        q = fminf(fmaxf(q, -128.f), 127.f);
        v = ibf16(q);
      }
      o[i] = v;
    }
  } else if (mode == 2) {    // conv weights: [Co][KP], k = khkw*Ci + ci, zero pad
    ushort* o = (ushort*)P.pa.out[t];
    const int CI = P.pa.ci[t], KK = P.pa.kk[t], KP = P.pa.kp[t], CO = P.pa.co[t];
    const int KT = CI * KK;
    for (int i = threadIdx.x; i < CO * KP; i += 256) {
      int co = i / KP, k = i % KP;
      ushort v = 0;
      if (k < KT) {
        int khkw = k / CI, ci = k % CI;
        float q = rintf(__fdiv_rn(in[(co * CI + ci) * KK + khkw], s));
        q = fminf(fmaxf(q, -128.f), 127.f);
        v = ibf16(q);
      }
      o[i] = v;
    }
  } else {
    float* o = (float*)P.pa.out[t];
    const int tc = P.pa.tc[t];
    const int nw = (mode == 1) ? n / tc : 1;
    for (int i = threadIdx.x; i < n; i += 256) {
      float q = rintf(__fdiv_rn(in[i], s));
      q = fminf(fmaxf(q, -128.f), 127.f);
      float v = __fmul_rn(q, s);
      if (mode == 1) o[(i % nw) * tc + i / nw] = v;
      else o[i] = v;
    }
  }
}

// ---- stage: x NCHW f32 -> NHWC4 ushort codes ----
__device__ void pack_x_stage(const NetParams& P, float s0) {
  const float inv = __fdiv_rn(1.0f, s0);
  for (int p = blockIdx.x * 256 + threadIdx.x; p < 16 * 50176;
       p += GRID_BLOCKS * 256) {
    int n = p / 50176, sp = p - n * 50176;
    const float* xb = P.x + (size_t)n * 150528 + sp;
    ushort4 o;
    o.x = ibf16(rintf(__fmul_rn(xb[0], inv)));
    o.y = ibf16(rintf(__fmul_rn(xb[50176], inv)));
    o.z = ibf16(rintf(__fmul_rn(xb[100352], inv)));
    o.w = 0;
    ((ushort4*)P.xc)[p] = o;
  }
}

// ---- stage: conv1 (Ci=3 NHWC4 codes, K=36 padded to 64, CO=32, pool) ----
__device__ void conv1_stage(const uint2* __restrict__ xc, const ushort* __restrict__ wt,
                            const float* __restrict__ sg, const float* __restrict__ sb,
                            float* __restrict__ out, float s_in, float s_w,
                            float* slot_out) {
  const int lane = threadIdx.x & 63;
  const int gwave = blockIdx.x * 4 + (threadIdx.x >> 6);
  const int quad = lane >> 4, col = lane & 15;
  const float S = __fmul_rn(s_in, s_w);
  const int ph = gwave / 56, pw = gwave % 56;      // 3136 pool-blocks/image
  const int h = 4 * ph + (col >> 2), w = 4 * pw + (col & 3);

  // per-lane taps for the two slabs: t = slab*8 + quad*2 + {0,1}
  int toff[4]; bool tval[4];
  #pragma unroll
  for (int s2 = 0; s2 < 2; s2++)
    #pragma unroll
    for (int j = 0; j < 2; j++) {
      int t = s2 * 8 + quad * 2 + j;
      int tc = min(t, 8);
      int kh = tc / 3, kw = tc - kh * 3;
      int hh = h + kh - 1, ww = w + kw - 1;
      tval[s2 * 2 + j] = (t < 9) && (hh >= 0) && (hh < 224) && (ww >= 0) && (ww < 224);
      toff[s2 * 2 + j] = min(max(hh, 0), 223) * 224 + min(max(ww, 0), 223);
    }

  float zmax = 0.f;
  for (int n = 0; n < 16; n++) {
    const uint2* xn = xc + (size_t)n * 50176;
    v4f acc[2];
    acc[0] = (v4f){0.f, 0.f, 0.f, 0.f};
    acc[1] = acc[0];
    #pragma unroll
    for (int s2 = 0; s2 < 2; s2++) {
      uint2 l0 = xn[toff[s2 * 2 + 0]];
      uint2 l1 = xn[toff[s2 * 2 + 1]];
      if (!tval[s2 * 2 + 0]) { l0.x = 0; l0.y = 0; }
      if (!tval[s2 * 2 + 1]) { l1.x = 0; l1.y = 0; }
      v8s a;
      ((uint2*)&a)[0] = l0;
      ((uint2*)&a)[1] = l1;
      #pragma unroll
      for (int c = 0; c < 2; c++) {
        v8s b = *(const v8s*)(wt + (size_t)(c * 16 + col) * 64 + s2 * 32 + quad * 8);
        acc[c] = __builtin_amdgcn_mfma_f32_16x16x32_bf16(a, b, acc[c], 0, 0, 0);
      }
    }
    #pragma unroll
    for (int c = 0; c < 2; c++) {
      const int cog = c * 16 + col;
      const float g = sg[cog], bb = sb[cog];
      float z[4];
      #pragma unroll
      for (int r2 = 0; r2 < 4; r2++) {
        float tt = __fmul_rn(acc[c][r2], S);                  // exact
        z[r2] = fmaxf(__fadd_rn(__fmul_rn(tt, g), bb), 0.f);  // matches XLA
      }
      float h0 = fmaxf(z[0], z[1]), h1 = fmaxf(z[2], z[3]);
      float o0 = fmaxf(h0, __shfl_xor(h0, 16));
      float o1 = fmaxf(h1, __shfl_xor(h1, 16));
      zmax = fmaxf(zmax, fmaxf(o0, o1));
      if (!(quad & 1)) {
        int oh = 2 * ph + (quad >> 1), ow = 2 * pw;
        float* op = out + ((size_t)((n * 112 + oh) * 112 + ow)) * 32 + cog;
        op[0] = o0; op[32] = o1;
      }
    }
  }
  float bm = block_reduce_max256(zmax);
  if (threadIdx.x == 0) slot_max_update(slot_out, bm);
}

// ---- stage: generic MFMA implicit-GEMM conv, quant-on-load (R4-exact) ----
// CSPL: output-channel split so small layers still fill all 3136 waves.
template <int CI, int H, int CO, bool K3, bool POOL, int CSPL>
__device__ void conv_stage(const float* __restrict__ in, const ushort* __restrict__ wt,
                           const float* __restrict__ sg, const float* __restrict__ sb,
                           float* __restrict__ out, float s_in, float s_w,
                           float* slot_out) {
  constexpr int W = H;
  constexpr int KT = (K3 ? 9 : 1) * CI;
  constexpr int SLABS = (KT + 31) / 32;
  constexpr int KP = SLABS * 32;
  constexpr int COT = CO / 16;
  constexpr int CGT = COT / CSPL;           // c-tiles per wave
  constexpr int HO = POOL ? H / 2 : H;
  constexpr int WO = POOL ? W / 2 : W;
  constexpr int PW = POOL ? (HO / 2) * (WO / 2) : (H * W) / 16;  // waves/image
  constexpr int WPI = PW * CSPL;
  constexpr int NSTEP = GRID_WAVES / WPI;
  static_assert(GRID_WAVES % WPI == 0, "grid/stage mismatch");
  static_assert(!POOL || CSPL == 1, "pool path assumes CSPL==1");

  const int lane = threadIdx.x & 63;
  const int gwave = blockIdx.x * 4 + (threadIdx.x >> 6);
  const int quad = lane >> 4, col = lane & 15;
  const float inv = __fdiv_rn(1.0f, s_in);     // exact: s_in = 2^e
  const float S = __fmul_rn(s_in, s_w);        // exact: both 2^e
  const int n0 = gwave / WPI;
  const int rem = gwave % WPI;
  const int r = rem / CSPL;                    // spatial id, loop-invariant
  const int cs = rem % CSPL;

  int h, w, ph = 0, pw = 0;
  if constexpr (POOL) {
    ph = r / (WO / 2); pw = r % (WO / 2);
    h = 4 * ph + (col >> 2); w = 4 * pw + (col & 3);
  } else {
    int p = r * 16 + col; h = p / W; w = p % W;
  }

  int toff[10]; bool tval[10];
  if constexpr (K3) {
    #pragma unroll
    for (int t = 0; t < 9; t++) {
      int kh = t / 3, kw = t % 3;
      int hh = h + kh - 1, ww = w + kw - 1;
      tval[t] = (hh >= 0) && (hh < H) && (ww >= 0) && (ww < W);
      toff[t] = (min(max(hh, 0), H - 1) * W + min(max(ww, 0), W - 1)) * CI;
    }
    toff[9] = toff[8]; tval[9] = false;
  }

  float zmax = 0.f;
  for (int n = n0; n < 16; n += NSTEP) {
    const float* ib = in + (size_t)n * H * W * CI;
    v4f acc[CGT];
    #pragma unroll
    for (int c = 0; c < CGT; c++) acc[c] = (v4f){0.f, 0.f, 0.f, 0.f};

    #pragma unroll
    for (int slab = 0; slab < SLABS; slab++) {
      const float* ap;
      bool tv = true;
      if constexpr (K3) {
        if constexpr (CI >= 32) {
          tv = tval[slab];
          ap = ib + toff[slab] + quad * 8;
        } else {   // CI==16: two taps per slab
          const bool hi = (quad & 2) != 0;
          tv = hi ? tval[2 * slab + 1] : tval[2 * slab];
          ap = ib + (hi ? toff[2 * slab + 1] : toff[2 * slab]) + (quad & 1) * 8;
        }
      } else {
        ap = ib + (h * W + w) * CI + (slab * 32 + quad * 8) % CI;
      }
      float4 f0 = ((const float4*)ap)[0];
      float4 f1 = ((const float4*)ap)[1];
      float ff[8] = {f0.x, f0.y, f0.z, f0.w, f1.x, f1.y, f1.z, f1.w};
      v8s a;
      #pragma unroll
      for (int j = 0; j < 8; j++)
        a[j] = (K3 && !tv) ? (short)0
                           : (short)ibf16(rintf(__fmul_rn(ff[j], inv)));
      #pragma unroll
      for (int c = 0; c < CGT; c++) {
        const int ct = cs * CGT + c;
        v8s b = *(const v8s*)(wt + (size_t)(ct * 16 + col) * KP + slab * 32 + quad * 8);
        acc[c] = __builtin_amdgcn_mfma_f32_16x16x32_bf16(a, b, acc[c], 0, 0, 0);
      }
    }

    #pragma unroll
    for (int c = 0; c < CGT; c++) {
      const int cog = (cs * CGT + c) * 16 + col;
      const float g = sg[cog], bb = sb[cog];
      float z[4];
      #pragma unroll
      for (int r2 = 0; r2 < 4; r2++) {
        float tt = __fmul_rn(acc[c][r2], S);
        z[r2] = fmaxf(__fadd_rn(__fmul_rn(tt, g), bb), 0.f);
      }
      if constexpr (POOL) {
        float h0 = fmaxf(z[0], z[1]), h1 = fmaxf(z[2], z[3]);
        float o0 = fmaxf(h0, __shfl_xor(h0, 16));
        float o1 = fmaxf(h1, __shfl_xor(h1, 16));
        zmax = fmaxf(zmax, fmaxf(o0, o1));
        if (!(quad & 1)) {
          int oh = 2 * ph + (quad >> 1), ow = 2 * pw;
          float* op = out + ((size_t)((n * HO + oh) * WO + ow)) * CO + cog;
          op[0] = o0; op[CO] = o1;
        }
      } else {
        const int pbase = n * H * W + r * 16 + quad * 4;
        #pragma unroll
        for (int r2 = 0; r2 < 4; r2++) {
          out[(size_t)(pbase + r2) * CO + cog] = z[r2];
          zmax = fmaxf(zmax, z[r2]);
        }
      }
    }
  }
  float bm = block_reduce_max256(zmax);
  if (threadIdx.x == 0) slot_max_update(slot_out, bm);
}

// ---- stage: avgpool (blocks 0..15), NHWC [16][784][64] ----
__device__ void avgpool_stage(const NetParams& P, float s) {
  __shared__ float red[256];
  const float inv = __fdiv_rn(1.0f, s);
  const int nn = blockIdx.x, co = threadIdx.x & 63, part = threadIdx.x >> 6;
  const float* p = P.rawB + (size_t)nn * 784 * 64;
  float sum = 0.f;
  for (int i = part * 196; i < part * 196 + 196; i++)
    sum += __fmul_rn(rintf(__fmul_rn(p[i * 64 + co], inv)), s);   // exact int sum
  red[threadIdx.x] = sum;
  __syncthreads();
  if (threadIdx.x < 64) {
    float tot = (red[co] + red[64 + co]) + (red[128 + co] + red[192 + co]);
    float mv = __fdiv_rn(tot, 784.0f);
    P.pool[nn * 64 + co] = mv;
    slot_max_update(P.slots + 13, mv);
  }
}

// ---- stage: quant(mean) -> fc1 -> relu -> quant -> fc2 (block 0) ----
__device__ void tail_stage(const NetParams& P) {
  __shared__ float xq[1024];
  __shared__ float hq[256];
  __shared__ float s2s;
  const int t = threadIdx.x;
  const float s = p2_scale_f(vload(P.slots + 13), 255.0f);
  const float inv = __fdiv_rn(1.0f, s);
  for (int i = t; i < 1024; i += 256)
    xq[i] = __fmul_rn(rintf(__fmul_rn(P.pool[i], inv)), s);
  __syncthreads();
  const int n = t >> 4, j = t & 15;
  float acc = 0.f;
  #pragma unroll 8
  for (int k = 0; k < 64; k++) acc += xq[n * 64 + k] * P.fw1[k * 16 + j];  // exact
  float z = fmaxf(__fadd_rn(acc, P.fb1[j]), 0.f);
  float bm = block_reduce_max256(z);
  if (t == 0) s2s = p2_scale_f(bm, 255.0f);
  __syncthreads();
  const float s2 = s2s, inv2 = __fdiv_rn(1.0f, s2);
  hq[t] = __fmul_rn(rintf(__fmul_rn(z, inv2)), s2);
  __syncthreads();
  if (t < 160) {
    const int n2 = t / 10, j2 = t % 10;
    float a2 = 0.f;
    #pragma unroll
    for (int k = 0; k < 16; k++) a2 += hq[n2 * 16 + k] * P.fw2[k * 10 + j2];  // exact
    P.out[t] = __fadd_rn(a2, P.fb2[j2]);
  }
}

#define PSC(i) p2_scale_f(vload(P.slots + (i)), 255.0f)
#define WSC(i) vload(P.wslot + (i))

__global__ __launch_bounds__(256, 4) void net_kernel(NetParams P) {
  unsigned* B = P.bars;

  prep_stage(P);
  gsync(B + 0);

  const float s0 = PSC(0);
  pack_x_stage(P, s0);
  gsync(B + 1);

  conv1_stage((const uint2*)P.xc, P.wq[0], P.sg[0], P.sb[0], P.rawA,
              s0, WSC(0), P.slots + 1);
  gsync(B + 2);

  conv_stage<32, 112, 16, true, true, 1>(P.rawA, P.wq[1], P.sg[1], P.sb[1], P.rawB,
                                         PSC(1), WSC(1), P.slots + 2);
  gsync(B + 3);
  conv_stage<16, 56, 16, false, false, 1>(P.rawB, P.wq[2], P.sg[2], P.sb[2], P.rawA,
                                          PSC(2), WSC(2), P.slots + 3);
  gsync(B + 4);
  conv_stage<16, 56, 32, true, false, 1>(P.rawA, P.wq[3], P.sg[3], P.sb[3], P.rawB,
                                         PSC(3), WSC(3), P.slots + 4);
  gsync(B + 5);
  conv_stage<32, 56, 32, false, false, 1>(P.rawB, P.wq[4], P.sg[4], P.sb[4], P.rawA,
                                          PSC(4), WSC(4), P.slots + 5);
  gsync(B + 6);
  conv_stage<32, 56, 64, true, true, 1>(P.rawA, P.wq[5], P.sg[5], P.sb[5], P.rawB,
                                        PSC(5), WSC(5), P.slots + 6);
  gsync(B + 7);
  conv_stage<64, 28, 32, false, false, 2>(P.rawB, P.wq[6], P.sg[6], P.sb[6], P.rawA,
                                          PSC(6), WSC(6), P.slots + 7);
  gsync(B + 8);
  conv_stage<32, 28, 64, true, false, 4>(P.rawA, P.wq[7], P.sg[7], P.sb[7], P.rawB,
                                         PSC(7), WSC(7), P.slots + 8);
  gsync(B + 9);
  conv_stage<64, 28, 32, false, false, 2>(P.rawB, P.wq[8], P.sg[8], P.sb[8], P.rawA,
                                          PSC(8), WSC(8), P.slots + 9);
  gsync(B + 10);
  conv_stage<32, 28, 64, true, false, 4>(P.rawA, P.wq[9], P.sg[9], P.sb[9], P.rawB,
                                         PSC(9), WSC(9), P.slots + 10);
  gsync(B + 11);
  conv_stage<64, 28, 32, false, false, 2>(P.rawB, P.wq[10], P.sg[10], P.sb[10], P.rawA,
                                          PSC(10), WSC(10), P.slots + 11);
  gsync(B + 12);
  conv_stage<32, 28, 64, true, false, 4>(P.rawA, P.wq[11], P.sg[11], P.sb[11], P.rawB,
                                         PSC(11), WSC(11), P.slots + 12);
  gsync(B + 13);

  if (blockIdx.x < 16) avgpool_stage(P, PSC(12));
  gsync(B + 14);
  if (blockIdx.x == 0) tail_stage(P);
}

extern "C" void kernel_launch(void* const* d_in, const int* in_sizes, int n_in,
                              void* d_out, int out_size, void* d_ws, size_t ws_size,
                              hipStream_t stream) {
  static const int h_ci[NL] = {3, 32, 16, 16, 32, 32, 64, 32, 64, 32, 64, 32};
  static const int h_co[NL] = {32, 16, 16, 32, 32, 64, 32, 64, 32, 64, 32, 64};
  static const int h_kk[NL] = {9, 9, 1, 9, 1, 9, 1, 9, 1, 9, 1, 9};
  static const int h_kp[NL] = {64, 288, 32, 160, 32, 288, 64, 288, 64, 288, 64, 288};

  float* ws = (float*)d_ws;
  NetParams np;
  np.slots = ws;                       // [0..13]
  np.wslot = ws + 16;                  // [0..11]
  np.bars  = (unsigned*)(ws + 32);     // [0..23] barrier counters
  size_t off = 64;                     // bytes [0,256) zeroed below

  for (int l = 0; l < NL; l++) {
    np.wq[l] = (const ushort*)(ws + off);
    off += (size_t)(h_co[l] * h_kp[l]) / 2;   // shorts -> float units
  }
  for (int l = 0; l < NL; l++) { np.sg[l] = ws + off; off += 64; }
  for (int l = 0; l < NL; l++) { np.sb[l] = ws + off; off += 64; }
  float* fw1q = ws + off; off += 1024;
  float* fb1q = ws + off; off += 16;
  float* fw2q = ws + off; off += 160;
  float* fb2q = ws + off; off += 16;
  np.fw1 = fw1q; np.fb1 = fb1q; np.fw2 = fw2q; np.fb2 = fb2q;
  np.rawA = ws + off; off += 6422528;               // max: conv1 out 25.7 MB
  np.rawB = ws + off; off += 1605632;               // max: conv32 out 6.4 MB
  np.xc   = (uint2*)(ws + off); off += 1605632;     // 802816 pixels * 8 B
  np.pool = ws + off; off += 1024;
  np.x = (const float*)d_in[0];
  np.out = (float*)d_out;

  PrepArgs& pa = np.pa;
  for (int l = 0; l < NL; l++) {
    pa.in[l] = (const float*)d_in[1 + 3 * l]; pa.out[l] = (void*)np.wq[l];
    pa.n[l] = h_co[l] * h_ci[l] * h_kk[l];
    pa.mode[l] = (l == 0) ? 3 : 2; pa.tc[l] = 0;
    pa.ci[l] = h_ci[l]; pa.kk[l] = h_kk[l]; pa.kp[l] = h_kp[l]; pa.co[l] = h_co[l];
    pa.in[12 + l] = (const float*)d_in[2 + 3 * l]; pa.out[12 + l] = (void*)np.sg[l];
    pa.n[12 + l] = h_co[l]; pa.mode[12 + l] = 0; pa.tc[12 + l] = 0;
    pa.ci[12 + l] = pa.kk[12 + l] = pa.kp[12 + l] = pa.co[12 + l] = 0;
    pa.in[24 + l] = (const float*)d_in[3 + 3 * l]; pa.out[24 + l] = (void*)np.sb[l];
    pa.n[24 + l] = h_co[l]; pa.mode[24 + l] = 0; pa.tc[24 + l] = 0;
    pa.ci[24 + l] = pa.kk[24 + l] = pa.kp[24 + l] = pa.co[24 + l] = 0;
  }
  pa.in[36] = (const float*)d_in[37]; pa.out[36] = (void*)fw1q;
  pa.n[36] = 1024; pa.mode[36] = 1; pa.tc[36] = 16;
  pa.ci[36] = pa.kk[36] = pa.kp[36] = pa.co[36] = 0;
  pa.in[37] = (const float*)d_in[38]; pa.out[37] = (void*)fb1q;
  pa.n[37] = 16; pa.mode[37] = 0; pa.tc[37] = 0;
  pa.ci[37] = pa.kk[37] = pa.kp[37] = pa.co[37] = 0;
  pa.in[38] = (const float*)d_in[39]; pa.out[38] = (void*)fw2q;
  pa.n[38] = 160; pa.mode[38] = 1; pa.tc[38] = 10;
  pa.ci[38] = pa.kk[38] = pa.kp[38] = pa.co[38] = 0;
  pa.in[39] = (const float*)d_in[40]; pa.out[39] = (void*)fb2q;
  pa.n[39] = 10; pa.mode[39] = 0; pa.tc[39] = 0;
  pa.ci[39] = pa.kk[39] = pa.kp[39] = pa.co[39] = 0;

  // zero slots + wslot + barrier counters (d_ws is poisoned 0xAA each launch)
  hipMemsetAsync(ws, 0, 256, stream);

  net_kernel<<<GRID_BLOCKS, 256, 0, stream>>>(np);
}

// Round 8
// 1362.557 us; speedup vs baseline: 1.0353x; 1.0353x over previous
//
#include <hip/hip_runtime.h>
#include <math.h>

#define NL 12
#define GRID_BLOCKS 784
#define GRID_WAVES 3136   // GRID_BLOCKS * 4

typedef short v8s __attribute__((ext_vector_type(8)));
typedef float v4f __attribute__((ext_vector_type(4)));

struct PrepArgs {
  const float* in[40];
  void* out[40];
  int n[40];      // input element count
  int mode[40];   // 0 plain fq, 1 transposed fq, 2 conv int-bf16, 3 conv1 int-bf16
  int tc[40];     // mode1 minor dim
  int ci[40], kk[40], kp[40], co[40];   // mode2 geometry
};

struct NetParams {
  PrepArgs pa;
  const float* x;        // NCHW f32 input
  uint2* xc;             // NHWC4 input codes, 1 pixel = 4 ushorts = uint2
  const ushort* wq[NL];
  const float* sg[NL];
  const float* sb[NL];
  const float* fw1; const float* fb1; const float* fw2; const float* fb2;
  float* rawA; float* rawB; float* pool;
  float* slots; float* wslot;
  unsigned* bars;        // software grid-barrier counters (zeroed host-side)
  float* out;
};

// power-of-two scale: 2^ceil(log2(max(maxv,1e-8)/levels)); f32 ratio (matches
// JAX), double log2/ceil so ceil lands on the right side of integer boundaries.
__device__ inline float p2_scale_f(float maxv, float levels) {
  float r = __fdiv_rn(fmaxf(maxv, 1e-8f), levels);
  return (float)exp2(ceil(log2((double)r)));
}

__device__ inline float vload(const float* p) { return *(volatile const float*)p; }

// ---- software grid barrier ----
// All GRID_BLOCKS co-resident (proven R6: barrier completed, absmax 0).
// Arrive: one device-scope RMW per block. WAIT WITH LOADS, NOT RMWs —
// R6 polled with atomicAdd(ctr,0): 784 serialized TCC RMWs per poll round
// ≈ 87 us/barrier. Agent-scope relaxed loads don't serialize.
// Release: __syncthreads (each thread's stores vmcnt-drained) + thread-0
// __threadfence (L2 writeback, device scope). Acquire: __threadfence
// (L2 invalidate) before __syncthreads.
__device__ inline void gsync(unsigned* ctr) {
  __syncthreads();
  if (threadIdx.x == 0) {
    __threadfence();
    unsigned arrived = __hip_atomic_fetch_add(ctr, 1u, __ATOMIC_RELAXED,
                                              __HIP_MEMORY_SCOPE_AGENT) + 1u;
    if (arrived < GRID_BLOCKS) {
      int tries = 0;
      while (__hip_atomic_load(ctr, __ATOMIC_RELAXED, __HIP_MEMORY_SCOPE_AGENT)
                 < GRID_BLOCKS && tries < (1 << 22)) {
        __builtin_amdgcn_s_sleep(8);
        tries++;
      }
    }
    __threadfence();
  }
  __syncthreads();
}

// arrive at a barrier without waiting (for blocks that exit before the stage
// guarded by it)
__device__ inline void garrive(unsigned* ctr) {
  __syncthreads();
  if (threadIdx.x == 0) {
    __threadfence();
    __hip_atomic_fetch_add(ctr, 1u, __ATOMIC_RELAXED, __HIP_MEMORY_SCOPE_AGENT);
  }
}

// blockDim 256. Result valid on thread 0. All threads must reach.
__device__ inline float block_reduce_max256(float v) {
  __shared__ float sm[4];
  #pragma unroll
  for (int off = 32; off; off >>= 1) v = fmaxf(v, __shfl_down(v, off));
  if ((threadIdx.x & 63) == 0) sm[threadIdx.x >> 6] = v;
  __syncthreads();
  if (threadIdx.x == 0) v = fmaxf(fmaxf(sm[0], sm[1]), fmaxf(sm[2], sm[3]));
  return v;
}

// v >= 0; non-negative float bits compare like unsigned. Monotone-growing slot
// makes the stale-read skip safe (any cached value was truly written).
__device__ inline void slot_max_update(float* slot, float v) {
  volatile unsigned int* su = (volatile unsigned int*)slot;
  unsigned int bits = __float_as_uint(v);
  if (bits > *su) atomicMax((unsigned int*)slot, bits);
}

// integer-valued float -> bf16 bits by truncation (exact for |v| <= 256)
__device__ inline ushort ibf16(float v) {
  return (ushort)(__float_as_uint(v) >> 16);
}

// ---- stage: weight prep (blocks 0..39) + input max (blocks 40..) ----
__device__ void prep_stage(const NetParams& P) {
  if (blockIdx.x >= 40) {
    const float4* x4 = (const float4*)P.x;
    const int nx4 = 16 * 3 * 224 * 224 / 4;
    float m = 0.f;
    for (int i = (blockIdx.x - 40) * 256 + threadIdx.x; i < nx4;
         i += (GRID_BLOCKS - 40) * 256) {
      float4 v = x4[i];
      m = fmaxf(fmaxf(fmaxf(m, v.x), fmaxf(v.y, v.z)), v.w);
    }
    float bm = block_reduce_max256(m);
    if (threadIdx.x == 0) slot_max_update(P.slots + 0, bm);
    return;
  }
  __shared__ float ssc;
  const int t = blockIdx.x;
  const float* in = P.pa.in[t];
  const int n = P.pa.n[t], mode = P.pa.mode[t];
  float m = 0.f;
  for (int i = threadIdx.x; i < n; i += 256) m = fmaxf(m, fabsf(in[i]));
  float bm = block_reduce_max256(m);
  if (threadIdx.x == 0) {
    ssc = p2_scale_f(bm, 127.0f);
    if (mode >= 2) P.wslot[t] = ssc;
  }
  __syncthreads();
  const float s = ssc;
  if (mode == 3) {           // conv1 weights: [32][64], k = tap*4 + ci
    ushort* o = (ushort*)P.pa.out[t];
    for (int i = threadIdx.x; i < 32 * 64; i += 256) {
      int co = i >> 6, k = i & 63, tap = k >> 2, ci = k & 3;
      ushort v = 0;
      if (tap < 9 && ci < 3) {
        float q = rintf(__fdiv_rn(in[(co * 3 + ci) * 9 + tap], s));
        q = fminf(fmaxf(q, -128.f), 127.f);
        v = ibf16(q);
      }
      o[i] = v;
    }
  } else if (mode == 2) {    // conv weights: [Co][KP], k = khkw*Ci + ci, zero pad
    ushort* o = (ushort*)P.pa.out[t];
    const int CI = P.pa.ci[t], KK = P.pa.kk[t], KP = P.pa.kp[t], CO = P.pa.co[t];
    const int KT = CI * KK;
    for (int i = threadIdx.x; i < CO * KP; i += 256) {
      int co = i / KP, k = i % KP;
      ushort v = 0;
      if (k < KT) {
        int khkw = k / CI, ci = k % CI;
        float q = rintf(__fdiv_rn(in[(co * CI + ci) * KK + khkw], s));
        q = fminf(fmaxf(q, -128.f), 127.f);
        v = ibf16(q);
      }
      o[i] = v;
    }
  } else {
    float* o = (float*)P.pa.out[t];
    const int tc = P.pa.tc[t];
    const int nw = (mode == 1) ? n / tc : 1;
    for (int i = threadIdx.x; i < n; i += 256) {
      float q = rintf(__fdiv_rn(in[i], s));
      q = fminf(fmaxf(q, -128.f), 127.f);
      float v = __fmul_rn(q, s);
      if (mode == 1) o[(i % nw) * tc + i / nw] = v;
      else o[i] = v;
    }
  }
}

// ---- stage: x NCHW f32 -> NHWC4 ushort codes ----
__device__ void pack_x_stage(const NetParams& P, float s0) {
  const float inv = __fdiv_rn(1.0f, s0);
  for (int p = blockIdx.x * 256 + threadIdx.x; p < 16 * 50176;
       p += GRID_BLOCKS * 256) {
    int n = p / 50176, sp = p - n * 50176;
    const float* xb = P.x + (size_t)n * 150528 + sp;
    ushort4 o;
    o.x = ibf16(rintf(__fmul_rn(xb[0], inv)));
    o.y = ibf16(rintf(__fmul_rn(xb[50176], inv)));
    o.z = ibf16(rintf(__fmul_rn(xb[100352], inv)));
    o.w = 0;
    ((ushort4*)P.xc)[p] = o;
  }
}

// ---- stage: conv1 (Ci=3 NHWC4 codes, K=36 padded to 64, CO=32, pool) ----
__device__ void conv1_stage(const uint2* __restrict__ xc, const ushort* __restrict__ wt,
                            const float* __restrict__ sg, const float* __restrict__ sb,
                            float* __restrict__ out, float s_in, float s_w,
                            float* slot_out) {
  const int lane = threadIdx.x & 63;
  const int gwave = blockIdx.x * 4 + (threadIdx.x >> 6);
  const int quad = lane >> 4, col = lane & 15;
  const float S = __fmul_rn(s_in, s_w);
  const int ph = gwave / 56, pw = gwave % 56;      // 3136 pool-blocks/image
  const int h = 4 * ph + (col >> 2), w = 4 * pw + (col & 3);

  // per-lane taps for the two slabs: t = slab*8 + quad*2 + {0,1}
  int toff[4]; bool tval[4];
  #pragma unroll
  for (int s2 = 0; s2 < 2; s2++)
    #pragma unroll
    for (int j = 0; j < 2; j++) {
      int t = s2 * 8 + quad * 2 + j;
      int tc = min(t, 8);
      int kh = tc / 3, kw = tc - kh * 3;
      int hh = h + kh - 1, ww = w + kw - 1;
      tval[s2 * 2 + j] = (t < 9) && (hh >= 0) && (hh < 224) && (ww >= 0) && (ww < 224);
      toff[s2 * 2 + j] = min(max(hh, 0), 223) * 224 + min(max(ww, 0), 223);
    }

  float zmax = 0.f;
  for (int n = 0; n < 16; n++) {
    const uint2* xn = xc + (size_t)n * 50176;
    v4f acc[2];
    acc[0] = (v4f){0.f, 0.f, 0.f, 0.f};
    acc[1] = acc[0];
    #pragma unroll
    for (int s2 = 0; s2 < 2; s2++) {
      uint2 l0 = xn[toff[s2 * 2 + 0]];
      uint2 l1 = xn[toff[s2 * 2 + 1]];
      if (!tval[s2 * 2 + 0]) { l0.x = 0; l0.y = 0; }
      if (!tval[s2 * 2 + 1]) { l1.x = 0; l1.y = 0; }
      v8s a;
      ((uint2*)&a)[0] = l0;
      ((uint2*)&a)[1] = l1;
      #pragma unroll
      for (int c = 0; c < 2; c++) {
        v8s b = *(const v8s*)(wt + (size_t)(c * 16 + col) * 64 + s2 * 32 + quad * 8);
        acc[c] = __builtin_amdgcn_mfma_f32_16x16x32_bf16(a, b, acc[c], 0, 0, 0);
      }
    }
    #pragma unroll
    for (int c = 0; c < 2; c++) {
      const int cog = c * 16 + col;
      const float g = sg[cog], bb = sb[cog];
      float z[4];
      #pragma unroll
      for (int r2 = 0; r2 < 4; r2++) {
        float tt = __fmul_rn(acc[c][r2], S);                  // exact
        z[r2] = fmaxf(__fadd_rn(__fmul_rn(tt, g), bb), 0.f);  // matches XLA
      }
      float h0 = fmaxf(z[0], z[1]), h1 = fmaxf(z[2], z[3]);
      float o0 = fmaxf(h0, __shfl_xor(h0, 16));
      float o1 = fmaxf(h1, __shfl_xor(h1, 16));
      zmax = fmaxf(zmax, fmaxf(o0, o1));
      if (!(quad & 1)) {
        int oh = 2 * ph + (quad >> 1), ow = 2 * pw;
        float* op = out + ((size_t)((n * 112 + oh) * 112 + ow)) * 32 + cog;
        op[0] = o0; op[32] = o1;
      }
    }
  }
  float bm = block_reduce_max256(zmax);
  if (threadIdx.x == 0) slot_max_update(slot_out, bm);
}

// ---- stage: generic MFMA implicit-GEMM conv, quant-on-load (R4-exact) ----
// CSPL: output-channel split so small layers still fill all 3136 waves.
template <int CI, int H, int CO, bool K3, bool POOL, int CSPL>
__device__ void conv_stage(const float* __restrict__ in, const ushort* __restrict__ wt,
                           const float* __restrict__ sg, const float* __restrict__ sb,
                           float* __restrict__ out, float s_in, float s_w,
                           float* slot_out) {
  constexpr int W = H;
  constexpr int KT = (K3 ? 9 : 1) * CI;
  constexpr int SLABS = (KT + 31) / 32;
  constexpr int KP = SLABS * 32;
  constexpr int COT = CO / 16;
  constexpr int CGT = COT / CSPL;           // c-tiles per wave
  constexpr int HO = POOL ? H / 2 : H;
  constexpr int WO = POOL ? W / 2 : W;
  constexpr int PW = POOL ? (HO / 2) * (WO / 2) : (H * W) / 16;  // waves/image
  constexpr int WPI = PW * CSPL;
  constexpr int NSTEP = GRID_WAVES / WPI;
  static_assert(GRID_WAVES % WPI == 0, "grid/stage mismatch");
  static_assert(!POOL || CSPL == 1, "pool path assumes CSPL==1");

  const int lane = threadIdx.x & 63;
  const int gwave = blockIdx.x * 4 + (threadIdx.x >> 6);
  const int quad = lane >> 4, col = lane & 15;
  const float inv = __fdiv_rn(1.0f, s_in);     // exact: s_in = 2^e
  const float S = __fmul_rn(s_in, s_w);        // exact: both 2^e
  const int n0 = gwave / WPI;
  const int rem = gwave % WPI;
  const int r = rem / CSPL;                    // spatial id, loop-invariant
  const int cs = rem % CSPL;

  int h, w, ph = 0, pw = 0;
  if constexpr (POOL) {
    ph = r / (WO / 2); pw = r % (WO / 2);
    h = 4 * ph + (col >> 2); w = 4 * pw + (col & 3);
  } else {
    int p = r * 16 + col; h = p / W; w = p % W;
  }

  int toff[10]; bool tval[10];
  if constexpr (K3) {
    #pragma unroll
    for (int t = 0; t < 9; t++) {
      int kh = t / 3, kw = t % 3;
      int hh = h + kh - 1, ww = w + kw - 1;
      tval[t] = (hh >= 0) && (hh < H) && (ww >= 0) && (ww < W);
      toff[t] = (min(max(hh, 0), H - 1) * W + min(max(ww, 0), W - 1)) * CI;
    }
    toff[9] = toff[8]; tval[9] = false;
  }

  float zmax = 0.f;
  for (int n = n0; n < 16; n += NSTEP) {
    const float* ib = in + (size_t)n * H * W * CI;
    v4f acc[CGT];
    #pragma unroll
    for (int c = 0; c < CGT; c++) acc[c] = (v4f){0.f, 0.f, 0.f, 0.f};

    #pragma unroll
    for (int slab = 0; slab < SLABS; slab++) {
      const float* ap;
      bool tv = true;
      if constexpr (K3) {
        if constexpr (CI >= 32) {
          tv = tval[slab];
          ap = ib + toff[slab] + quad * 8;
        } else {   // CI==16: two taps per slab
          const bool hi = (quad & 2) != 0;
          tv = hi ? tval[2 * slab + 1] : tval[2 * slab];
          ap = ib + (hi ? toff[2 * slab + 1] : toff[2 * slab]) + (quad & 1) * 8;
        }
      } else {
        ap = ib + (h * W + w) * CI + (slab * 32 + quad * 8) % CI;
      }
      float4 f0 = ((const float4*)ap)[0];
      float4 f1 = ((const float4*)ap)[1];
      float ff[8] = {f0.x, f0.y, f0.z, f0.w, f1.x, f1.y, f1.z, f1.w};
      v8s a;
      #pragma unroll
      for (int j = 0; j < 8; j++)
        a[j] = (K3 && !tv) ? (short)0
                           : (short)ibf16(rintf(__fmul_rn(ff[j], inv)));
      #pragma unroll
      for (int c = 0; c < CGT; c++) {
        const int ct = cs * CGT + c;
        v8s b = *(const v8s*)(wt + (size_t)(ct * 16 + col) * KP + slab * 32 + quad * 8);
        acc[c] = __builtin_amdgcn_mfma_f32_16x16x32_bf16(a, b, acc[c], 0, 0, 0);
      }
    }

    #pragma unroll
    for (int c = 0; c < CGT; c++) {
      const int cog = (cs * CGT + c) * 16 + col;
      const float g = sg[cog], bb = sb[cog];
      float z[4];
      #pragma unroll
      for (int r2 = 0; r2 < 4; r2++) {
        float tt = __fmul_rn(acc[c][r2], S);
        z[r2] = fmaxf(__fadd_rn(__fmul_rn(tt, g), bb), 0.f);
      }
      if constexpr (POOL) {
        float h0 = fmaxf(z[0], z[1]), h1 = fmaxf(z[2], z[3]);
        float o0 = fmaxf(h0, __shfl_xor(h0, 16));
        float o1 = fmaxf(h1, __shfl_xor(h1, 16));
        zmax = fmaxf(zmax, fmaxf(o0, o1));
        if (!(quad & 1)) {
          int oh = 2 * ph + (quad >> 1), ow = 2 * pw;
          float* op = out + ((size_t)((n * HO + oh) * WO + ow)) * CO + cog;
          op[0] = o0; op[CO] = o1;
        }
      } else {
        const int pbase = n * H * W + r * 16 + quad * 4;
        #pragma unroll
        for (int r2 = 0; r2 < 4; r2++) {
          out[(size_t)(pbase + r2) * CO + cog] = z[r2];
          zmax = fmaxf(zmax, z[r2]);
        }
      }
    }
  }
  float bm = block_reduce_max256(zmax);
  if (threadIdx.x == 0) slot_max_update(slot_out, bm);
}

// ---- stage: avgpool (blocks 0..15), NHWC [16][784][64] ----
__device__ void avgpool_stage(const NetParams& P, float s) {
  __shared__ float red[256];
  const float inv = __fdiv_rn(1.0f, s);
  const int nn = blockIdx.x, co = threadIdx.x & 63, part = threadIdx.x >> 6;
  const float* p = P.rawB + (size_t)nn * 784 * 64;
  float sum = 0.f;
  for (int i = part * 196; i < part * 196 + 196; i++)
    sum += __fmul_rn(rintf(__fmul_rn(p[i * 64 + co], inv)), s);   // exact int sum
  red[threadIdx.x] = sum;
  __syncthreads();
  if (threadIdx.x < 64) {
    float tot = (red[co] + red[64 + co]) + (red[128 + co] + red[192 + co]);
    float mv = __fdiv_rn(tot, 784.0f);
    P.pool[nn * 64 + co] = mv;
    slot_max_update(P.slots + 13, mv);
  }
}

// ---- stage: quant(mean) -> fc1 -> relu -> quant -> fc2 (block 0) ----
__device__ void tail_stage(const NetParams& P) {
  __shared__ float xq[1024];
  __shared__ float hq[256];
  __shared__ float s2s;
  const int t = threadIdx.x;
  const float s = p2_scale_f(vload(P.slots + 13), 255.0f);
  const float inv = __fdiv_rn(1.0f, s);
  for (int i = t; i < 1024; i += 256)
    xq[i] = __fmul_rn(rintf(__fmul_rn(P.pool[i], inv)), s);
  __syncthreads();
  const int n = t >> 4, j = t & 15;
  float acc = 0.f;
  #pragma unroll 8
  for (int k = 0; k < 64; k++) acc += xq[n * 64 + k] * P.fw1[k * 16 + j];  // exact
  float z = fmaxf(__fadd_rn(acc, P.fb1[j]), 0.f);
  float bm = block_reduce_max256(z);
  if (t == 0) s2s = p2_scale_f(bm, 255.0f);
  __syncthreads();
  const float s2 = s2s, inv2 = __fdiv_rn(1.0f, s2);
  hq[t] = __fmul_rn(rintf(__fmul_rn(z, inv2)), s2);
  __syncthreads();
  if (t < 160) {
    const int n2 = t / 10, j2 = t % 10;
    float a2 = 0.f;
    #pragma unroll
    for (int k = 0; k < 16; k++) a2 += hq[n2 * 16 + k] * P.fw2[k * 10 + j2];  // exact
    P.out[t] = __fadd_rn(a2, P.fb2[j2]);
  }
}

#define PSC(i) p2_scale_f(vload(P.slots + (i)), 255.0f)
#define WSC(i) vload(P.wslot + (i))

__global__ __launch_bounds__(256, 4) void net_kernel(NetParams P) {
  unsigned* B = P.bars;

  prep_stage(P);
  gsync(B + 0);

  const float s0 = PSC(0);
  pack_x_stage(P, s0);
  gsync(B + 1);

  conv1_stage((const uint2*)P.xc, P.wq[0], P.sg[0], P.sb[0], P.rawA,
              s0, WSC(0), P.slots + 1);
  gsync(B + 2);

  conv_stage<32, 112, 16, true, true, 1>(P.rawA, P.wq[1], P.sg[1], P.sb[1], P.rawB,
                                         PSC(1), WSC(1), P.slots + 2);
  gsync(B + 3);
  conv_stage<16, 56, 16, false, false, 1>(P.rawB, P.wq[2], P.sg[2], P.sb[2], P.rawA,
                                          PSC(2), WSC(2), P.slots + 3);
  gsync(B + 4);
  conv_stage<16, 56, 32, true, false, 1>(P.rawA, P.wq[3], P.sg[3], P.sb[3], P.rawB,
                                         PSC(3), WSC(3), P.slots + 4);
  gsync(B + 5);
  conv_stage<32, 56, 32, false, false, 1>(P.rawB, P.wq[4], P.sg[4], P.sb[4], P.rawA,
                                          PSC(4), WSC(4), P.slots + 5);
  gsync(B + 6);
  conv_stage<32, 56, 64, true, true, 1>(P.rawA, P.wq[5], P.sg[5], P.sb[5], P.rawB,
                                        PSC(5), WSC(5), P.slots + 6);
  gsync(B + 7);
  conv_stage<64, 28, 32, false, false, 2>(P.rawB, P.wq[6], P.sg[6], P.sb[6], P.rawA,
                                          PSC(6), WSC(6), P.slots + 7);
  gsync(B + 8);
  conv_stage<32, 28, 64, true, false, 4>(P.rawA, P.wq[7], P.sg[7], P.sb[7], P.rawB,
                                         PSC(7), WSC(7), P.slots + 8);
  gsync(B + 9);
  conv_stage<64, 28, 32, false, false, 2>(P.rawB, P.wq[8], P.sg[8], P.sb[8], P.rawA,
                                          PSC(8), WSC(8), P.slots + 9);
  gsync(B + 10);
  conv_stage<32, 28, 64, true, false, 4>(P.rawA, P.wq[9], P.sg[9], P.sb[9], P.rawB,
                                         PSC(9), WSC(9), P.slots + 10);
  gsync(B + 11);
  conv_stage<64, 28, 32, false, false, 2>(P.rawB, P.wq[10], P.sg[10], P.sb[10], P.rawA,
                                          PSC(10), WSC(10), P.slots + 11);
  gsync(B + 12);
  conv_stage<32, 28, 64, true, false, 4>(P.rawA, P.wq[11], P.sg[11], P.sb[11], P.rawB,
                                         PSC(11), WSC(11), P.slots + 12);
  gsync(B + 13);

  // avgpool runs on blocks 0..15; everyone else arrives at the final barrier
  // and exits (no pointless polling during the serial tail).
  if (blockIdx.x >= 16) {
    garrive(B + 14);
    return;
  }
  avgpool_stage(P, PSC(12));
  gsync(B + 14);
  if (blockIdx.x == 0) tail_stage(P);
}

extern "C" void kernel_launch(void* const* d_in, const int* in_sizes, int n_in,
                              void* d_out, int out_size, void* d_ws, size_t ws_size,
                              hipStream_t stream) {
  static const int h_ci[NL] = {3, 32, 16, 16, 32, 32, 64, 32, 64, 32, 64, 32};
  static const int h_co[NL] = {32, 16, 16, 32, 32, 64, 32, 64, 32, 64, 32, 64};
  static const int h_kk[NL] = {9, 9, 1, 9, 1, 9, 1, 9, 1, 9, 1, 9};
  static const int h_kp[NL] = {64, 288, 32, 160, 32, 288, 64, 288, 64, 288, 64, 288};

  float* ws = (float*)d_ws;
  NetParams np;
  np.slots = ws;                       // [0..13]
  np.wslot = ws + 16;                  // [0..11]
  np.bars  = (unsigned*)(ws + 32);     // [0..23] barrier counters
  size_t off = 64;                     // bytes [0,256) zeroed below

  for (int l = 0; l < NL; l++) {
    np.wq[l] = (const ushort*)(ws + off);
    off += (size_t)(h_co[l] * h_kp[l]) / 2;   // shorts -> float units
  }
  for (int l = 0; l < NL; l++) { np.sg[l] = ws + off; off += 64; }
  for (int l = 0; l < NL; l++) { np.sb[l] = ws + off; off += 64; }
  float* fw1q = ws + off; off += 1024;
  float* fb1q = ws + off; off += 16;
  float* fw2q = ws + off; off += 160;
  float* fb2q = ws + off; off += 16;
  np.fw1 = fw1q; np.fb1 = fb1q; np.fw2 = fw2q; np.fb2 = fb2q;
  np.rawA = ws + off; off += 6422528;               // max: conv1 out 25.7 MB
  np.rawB = ws + off; off += 1605632;               // max: conv32 out 6.4 MB
  np.xc   = (uint2*)(ws + off); off += 1605632;     // 802816 pixels * 8 B
  np.pool = ws + off; off += 1024;
  np.x = (const float*)d_in[0];
  np.out = (float*)d_out;

  PrepArgs& pa = np.pa;
  for (int l = 0; l < NL; l++) {
    pa.in[l] = (const float*)d_in[1 + 3 * l]; pa.out[l] = (void*)np.wq[l];
    pa.n[l] = h_co[l] * h_ci[l] * h_kk[l];
    pa.mode[l] = (l == 0) ? 3 : 2; pa.tc[l] = 0;
    pa.ci[l] = h_ci[l]; pa.kk[l] = h_kk[l]; pa.kp[l] = h_kp[l]; pa.co[l] = h_co[l];
    pa.in[12 + l] = (const float*)d_in[2 + 3 * l]; pa.out[12 + l] = (void*)np.sg[l];
    pa.n[12 + l] = h_co[l]; pa.mode[12 + l] = 0; pa.tc[12 + l] = 0;
    pa.ci[12 + l] = pa.kk[12 + l] = pa.kp[12 + l] = pa.co[12 + l] = 0;
    pa.in[24 + l] = (const float*)d_in[3 + 3 * l]; pa.out[24 + l] = (void*)np.sb[l];
    pa.n[24 + l] = h_co[l]; pa.mode[24 + l] = 0; pa.tc[24 + l] = 0;
    pa.ci[24 + l] = pa.kk[24 + l] = pa.kp[24 + l] = pa.co[24 + l] = 0;
  }
  pa.in[36] = (const float*)d_in[37]; pa.out[36] = (void*)fw1q;
  pa.n[36] = 1024; pa.mode[36] = 1; pa.tc[36] = 16;
  pa.ci[36] = pa.kk[36] = pa.kp[36] = pa.co[36] = 0;
  pa.in[37] = (const float*)d_in[38]; pa.out[37] = (void*)fb1q;
  pa.n[37] = 16; pa.mode[37] = 0; pa.tc[37] = 0;
  pa.ci[37] = pa.kk[37] = pa.kp[37] = pa.co[37] = 0;
  pa.in[38] = (const float*)d_in[39]; pa.out[38] = (void*)fw2q;
  pa.n[38] = 160; pa.mode[38] = 1; pa.tc[38] = 10;
  pa.ci[38] = pa.kk[38] = pa.kp[38] = pa.co[38] = 0;
  pa.in[39] = (const float*)d_in[40]; pa.out[39] = (void*)fb2q;
  pa.n[39] = 10; pa.mode[39] = 0; pa.tc[39] = 0;
  pa.ci[39] = pa.kk[39] = pa.kp[39] = pa.co[39] = 0;

  // zero slots + wslot + barrier counters (d_ws is poisoned 0xAA each launch)
  hipMemsetAsync(ws, 0, 256, stream);

  net_kernel<<<GRID_BLOCKS, 256, 0, stream>>>(np);
}

// Round 9
// 464.305 us; speedup vs baseline: 3.0382x; 2.9346x over previous
//
#include <hip/hip_runtime.h>
#include <math.h>

#define NL 12

typedef short v8s __attribute__((ext_vector_type(8)));
typedef float v4f __attribute__((ext_vector_type(4)));

struct PrepArgs {
  const float* in[40];
  void* out[40];
  int n[40];      // input element count
  int mode[40];   // 0 plain fq, 1 transposed fq, 2 conv int-bf16, 3 conv1 int-bf16
  int tc[40];     // mode1 minor dim
  int ci[40], kk[40], kp[40], co[40];   // mode2 geometry
};

// power-of-two scale: 2^ceil(log2(max(maxv,1e-8)/levels)); f32 ratio (matches
// JAX), double log2/ceil so ceil lands on the right side of integer boundaries.
__device__ inline float p2_scale_f(float maxv, float levels) {
  float r = __fdiv_rn(fmaxf(maxv, 1e-8f), levels);
  return (float)exp2(ceil(log2((double)r)));
}

// blockDim 256. Result valid on thread 0. All threads must reach.
__device__ inline float block_reduce_max256(float v) {
  __shared__ float sm[4];
  #pragma unroll
  for (int off = 32; off; off >>= 1) v = fmaxf(v, __shfl_down(v, off));
  if ((threadIdx.x & 63) == 0) sm[threadIdx.x >> 6] = v;
  __syncthreads();
  if (threadIdx.x == 0) v = fmaxf(fmaxf(sm[0], sm[1]), fmaxf(sm[2], sm[3]));
  return v;
}

// v >= 0; non-negative float bits compare like unsigned. Read-skip culls the
// serialized same-line RMW train (R4 prep lesson: ~28 ns per serialized RMW).
__device__ inline void slot_max_update(float* slot, float v) {
  volatile unsigned int* su = (volatile unsigned int*)slot;
  unsigned int bits = __float_as_uint(v);
  if (bits > *su) atomicMax((unsigned int*)slot, bits);
}

// integer-valued float -> bf16 bits by truncation (exact for |v| <= 256)
__device__ inline ushort ibf16(float v) {
  return (ushort)(__float_as_uint(v) >> 16);
}

// blocks [0,40): per-tensor weight prep. blocks [40,168): float4 x-max.
__global__ void prep_kernel(PrepArgs a, float* wslot,
                            const float4* __restrict__ x4, int nx4, float* slot0) {
  if (blockIdx.x >= 40) {
    float m = 0.f;
    for (int i = (blockIdx.x - 40) * 256 + threadIdx.x; i < nx4; i += 128 * 256) {
      float4 v = x4[i];
      m = fmaxf(fmaxf(fmaxf(m, v.x), fmaxf(v.y, v.z)), v.w);
    }
    float bm = block_reduce_max256(m);
    if (threadIdx.x == 0) slot_max_update(slot0, bm);
    return;
  }
  __shared__ float ssc;
  const int t = blockIdx.x;
  const float* in = a.in[t];
  const int n = a.n[t], mode = a.mode[t];
  float m = 0.f;
  for (int i = threadIdx.x; i < n; i += 256) m = fmaxf(m, fabsf(in[i]));
  float bm = block_reduce_max256(m);
  if (threadIdx.x == 0) {
    ssc = p2_scale_f(bm, 127.0f);
    if (mode >= 2) wslot[t] = ssc;
  }
  __syncthreads();
  const float s = ssc;
  if (mode == 3) {           // conv1 weights: [32][64], k = tap*4 + ci (NHWC4)
    ushort* o = (ushort*)a.out[t];
    for (int i = threadIdx.x; i < 32 * 64; i += 256) {
      int co = i >> 6, k = i & 63, tap = k >> 2, ci = k & 3;
      ushort v = 0;
      if (tap < 9 && ci < 3) {
        float q = rintf(__fdiv_rn(in[(co * 3 + ci) * 9 + tap], s));
        q = fminf(fmaxf(q, -128.f), 127.f);
        v = ibf16(q);
      }
      o[i] = v;
    }
  } else if (mode == 2) {    // conv weights: [Co][KP], k = khkw*Ci + ci, zero pad
    ushort* o = (ushort*)a.out[t];
    const int CI = a.ci[t], KK = a.kk[t], KP = a.kp[t], CO = a.co[t];
    const int KT = CI * KK;
    for (int i = threadIdx.x; i < CO * KP; i += 256) {
      int co = i / KP, k = i % KP;
      ushort v = 0;
      if (k < KT) {
        int khkw = k / CI, ci = k % CI;
        float q = rintf(__fdiv_rn(in[(co * CI + ci) * KK + khkw], s));
        q = fminf(fmaxf(q, -128.f), 127.f);
        v = ibf16(q);
      }
      o[i] = v;
    }
  } else {
    float* o = (float*)a.out[t];
    const int tc = a.tc[t];
    const int nw = (mode == 1) ? n / tc : 1;
    for (int i = threadIdx.x; i < n; i += 256) {
      float q = rintf(__fdiv_rn(in[i], s));
      q = fminf(fmaxf(q, -128.f), 127.f);
      float v = __fmul_rn(q, s);
      if (mode == 1) o[(i % nw) * tc + i / nw] = v;
      else o[i] = v;
    }
  }
}

// x NCHW f32 -> NHWC4 ushort codes (R7-verified layout: pixel = 4 ushorts)
__global__ void pack_x_kernel(const float* __restrict__ x, ushort4* __restrict__ xc,
                              const float* __restrict__ slot0) {
  __shared__ float sinv;
  if (threadIdx.x == 0) sinv = __fdiv_rn(1.0f, p2_scale_f(slot0[0], 255.0f));
  __syncthreads();
  const float inv = sinv;
  for (int p = blockIdx.x * 256 + threadIdx.x; p < 16 * 50176; p += 784 * 256) {
    int n = p / 50176, sp = p - n * 50176;
    const float* xb = x + (size_t)n * 150528 + sp;
    ushort4 o;
    o.x = ibf16(rintf(__fmul_rn(xb[0], inv)));
    o.y = ibf16(rintf(__fmul_rn(xb[50176], inv)));
    o.z = ibf16(rintf(__fmul_rn(xb[100352], inv)));
    o.w = 0;
    xc[p] = o;
  }
}

// conv1: NHWC4 codes, K=36 padded to 64 (2 slabs), CO=32, pool 224->112.
// One (n,ph,pw) 4x4 patch per wave; uint2 per-lane loads (coalesced).
__global__ __launch_bounds__(256)
void conv1_mfma(const uint2* __restrict__ xc, const ushort* __restrict__ wt,
                const float* __restrict__ sg, const float* __restrict__ sb,
                float* __restrict__ out, const float* __restrict__ slot_in,
                const float* __restrict__ wslotp, float* slot_out) {
  const int lane = threadIdx.x & 63, widx = threadIdx.x >> 6;
  const int quad = lane >> 4, col = lane & 15;
  const float s_in = p2_scale_f(slot_in[0], 255.0f);
  const float S = __fmul_rn(s_in, wslotp[0]);   // exact: both 2^e
  const int wv = blockIdx.x * 4 + widx;         // [0, 50176)
  const int n = wv / 3136, r = wv % 3136;
  const int ph = r / 56, pw = r % 56;
  const int h = 4 * ph + (col >> 2), w = 4 * pw + (col & 3);

  // taps for slab s2: t = s2*8 + quad*2 + {0,1}; A elem j: k = s2*32+quad*8+j
  int toff[4]; bool tval[4];
  #pragma unroll
  for (int s2 = 0; s2 < 2; s2++)
    #pragma unroll
    for (int j = 0; j < 2; j++) {
      int t = s2 * 8 + quad * 2 + j;
      int tc = min(t, 8);
      int kh = tc / 3, kw = tc - kh * 3;
      int hh = h + kh - 1, ww = w + kw - 1;
      tval[s2 * 2 + j] = (t < 9) && (hh >= 0) && (hh < 224) && (ww >= 0) && (ww < 224);
      toff[s2 * 2 + j] = min(max(hh, 0), 223) * 224 + min(max(ww, 0), 223);
    }

  const uint2* xn = xc + (size_t)n * 50176;
  v4f acc[2];
  acc[0] = (v4f){0.f, 0.f, 0.f, 0.f};
  acc[1] = acc[0];
  #pragma unroll
  for (int s2 = 0; s2 < 2; s2++) {
    uint2 l0 = xn[toff[s2 * 2 + 0]];
    uint2 l1 = xn[toff[s2 * 2 + 1]];
    if (!tval[s2 * 2 + 0]) { l0.x = 0; l0.y = 0; }
    if (!tval[s2 * 2 + 1]) { l1.x = 0; l1.y = 0; }
    v8s a;
    ((uint2*)&a)[0] = l0;
    ((uint2*)&a)[1] = l1;
    #pragma unroll
    for (int c = 0; c < 2; c++) {
      v8s b = *(const v8s*)(wt + (size_t)(c * 16 + col) * 64 + s2 * 32 + quad * 8);
      acc[c] = __builtin_amdgcn_mfma_f32_16x16x32_bf16(a, b, acc[c], 0, 0, 0);
    }
  }
  float zmax = 0.f;
  #pragma unroll
  for (int c = 0; c < 2; c++) {
    const int cog = c * 16 + col;
    const float g = sg[cog], bb = sb[cog];
    float z[4];
    #pragma unroll
    for (int r2 = 0; r2 < 4; r2++) {
      float tt = __fmul_rn(acc[c][r2], S);                  // exact
      z[r2] = fmaxf(__fadd_rn(__fmul_rn(tt, g), bb), 0.f);  // matches XLA
    }
    float h0 = fmaxf(z[0], z[1]), h1 = fmaxf(z[2], z[3]);
    float o0 = fmaxf(h0, __shfl_xor(h0, 16));
    float o1 = fmaxf(h1, __shfl_xor(h1, 16));
    zmax = fmaxf(zmax, fmaxf(o0, o1));
    if (!(quad & 1)) {
      int oh = 2 * ph + (quad >> 1), ow = 2 * pw;
      float* op = out + ((size_t)((n * 112 + oh) * 112 + ow)) * 32 + cog;
      op[0] = o0; op[32] = o1;
    }
  }
  float bm = block_reduce_max256(zmax);
  if (threadIdx.x == 0) slot_max_update(slot_out, bm);
}

// ---- generic MFMA implicit-GEMM conv, quant-on-load (R4-exact) ----
// CSPL: output-channel split (R7-verified) so 28x28 layers keep occupancy up.
template <int CI, int H, int CO, bool K3, bool POOL, int CSPL>
__global__ __launch_bounds__(256)
void conv_mfma(const float* __restrict__ in, const ushort* __restrict__ wt,
               const float* __restrict__ sg, const float* __restrict__ sb,
               float* __restrict__ out, const float* __restrict__ slot_in,
               const float* __restrict__ wslotp, float* slot_out) {
  constexpr int W = H;
  constexpr int KT = (K3 ? 9 : 1) * CI;
  constexpr int SLABS = (KT + 31) / 32;
  constexpr int KP = SLABS * 32;
  constexpr int COT = CO / 16;
  constexpr int CGT = COT / CSPL;
  constexpr int HO = POOL ? H / 2 : H;
  constexpr int WO = POOL ? W / 2 : W;
  constexpr int PW = POOL ? (HO / 2) * (WO / 2) : (H * W) / 16;  // waves/image
  static_assert(!POOL || CSPL == 1, "pool path assumes CSPL==1");

  const int lane = threadIdx.x & 63, widx = threadIdx.x >> 6;
  const int quad = lane >> 4, col = lane & 15;
  const float s_in = p2_scale_f(slot_in[0], 255.0f);
  const float inv = __fdiv_rn(1.0f, s_in);     // exact: s_in = 2^e
  const float S = __fmul_rn(s_in, wslotp[0]);  // exact: both 2^e
  const int gwave = blockIdx.x * 4 + widx;     // [0, 16*PW*CSPL)
  const int n = gwave / (PW * CSPL);
  const int rem = gwave % (PW * CSPL);
  const int r = rem / CSPL;                    // cs innermost: block's 4 waves
  const int cs = rem % CSPL;                   // share A data in cache

  int h, w, ph = 0, pw = 0;
  if constexpr (POOL) {
    ph = r / (WO / 2); pw = r % (WO / 2);
    h = 4 * ph + (col >> 2); w = 4 * pw + (col & 3);
  } else {
    int p = r * 16 + col; h = p / W; w = p % W;
  }

  int toff[10]; bool tval[10];
  if constexpr (K3) {
    #pragma unroll
    for (int t = 0; t < 9; t++) {
      int kh = t / 3, kw = t % 3;
      int hh = h + kh - 1, ww = w + kw - 1;
      tval[t] = (hh >= 0) && (hh < H) && (ww >= 0) && (ww < W);
      toff[t] = (min(max(hh, 0), H - 1) * W + min(max(ww, 0), W - 1)) * CI;
    }
    toff[9] = toff[8]; tval[9] = false;
  }

  const float* ib = in + (size_t)n * H * W * CI;
  v4f acc[CGT];
  #pragma unroll
  for (int c = 0; c < CGT; c++) acc[c] = (v4f){0.f, 0.f, 0.f, 0.f};

  #pragma unroll
  for (int slab = 0; slab < SLABS; slab++) {
    const float* ap;
    bool tv = true;
    if constexpr (K3) {
      if constexpr (CI >= 32) {
        tv = tval[slab];
        ap = ib + toff[slab] + quad * 8;
      } else {   // CI==16: two taps per slab
        const bool hi = (quad & 2) != 0;
        tv = hi ? tval[2 * slab + 1] : tval[2 * slab];
        ap = ib + (hi ? toff[2 * slab + 1] : toff[2 * slab]) + (quad & 1) * 8;
      }
    } else {
      ap = ib + (h * W + w) * CI + (slab * 32 + quad * 8) % CI;
    }
    float4 f0 = ((const float4*)ap)[0];
    float4 f1 = ((const float4*)ap)[1];
    float ff[8] = {f0.x, f0.y, f0.z, f0.w, f1.x, f1.y, f1.z, f1.w};
    v8s a;
    #pragma unroll
    for (int j = 0; j < 8; j++)
      a[j] = (K3 && !tv) ? (short)0
                         : (short)ibf16(rintf(__fmul_rn(ff[j], inv)));
    #pragma unroll
    for (int c = 0; c < CGT; c++) {
      const int ct = cs * CGT + c;
      v8s b = *(const v8s*)(wt + (size_t)(ct * 16 + col) * KP + slab * 32 + quad * 8);
      acc[c] = __builtin_amdgcn_mfma_f32_16x16x32_bf16(a, b, acc[c], 0, 0, 0);
    }
  }

  float zmax = 0.f;
  #pragma unroll
  for (int c = 0; c < CGT; c++) {
    const int cog = (cs * CGT + c) * 16 + col;
    const float g = sg[cog], bb = sb[cog];
    float z[4];
    #pragma unroll
    for (int r2 = 0; r2 < 4; r2++) {
      float tt = __fmul_rn(acc[c][r2], S);
      z[r2] = fmaxf(__fadd_rn(__fmul_rn(tt, g), bb), 0.f);
    }
    if constexpr (POOL) {
      float h0 = fmaxf(z[0], z[1]), h1 = fmaxf(z[2], z[3]);
      float o0 = fmaxf(h0, __shfl_xor(h0, 16));
      float o1 = fmaxf(h1, __shfl_xor(h1, 16));
      zmax = fmaxf(zmax, fmaxf(o0, o1));
      if (!(quad & 1)) {
        int oh = 2 * ph + (quad >> 1), ow = 2 * pw;
        float* op = out + ((size_t)((n * HO + oh) * WO + ow)) * CO + cog;
        op[0] = o0; op[CO] = o1;
      }
    } else {
      const int pbase = n * H * W + r * 16 + quad * 4;
      #pragma unroll
      for (int r2 = 0; r2 < 4; r2++) {
        out[(size_t)(pbase + r2) * CO + cog] = z[r2];
        zmax = fmaxf(zmax, z[r2]);
      }
    }
  }
  float bm = block_reduce_max256(zmax);
  if (threadIdx.x == 0) slot_max_update(slot_out, bm);
}

// NHWC avgpool: in [16][784][64] raw; quantize on read, exact sum, one divide.
__global__ void avgpool_kernel(const float* __restrict__ in, float* __restrict__ out,
                               const float* __restrict__ slot_in, float* slot_out) {
  __shared__ float red[256];
  const float s = p2_scale_f(slot_in[0], 255.0f);
  const float inv = __fdiv_rn(1.0f, s);
  const int nn = blockIdx.x, co = threadIdx.x & 63, part = threadIdx.x >> 6;
  const float* p = in + (size_t)nn * 784 * 64;
  float sum = 0.f;
  for (int i = part * 196; i < part * 196 + 196; i++)
    sum += __fmul_rn(rintf(__fmul_rn(p[i * 64 + co], inv)), s);   // exact int sum
  red[threadIdx.x] = sum;
  __syncthreads();
  if (threadIdx.x < 64) {
    float tot = (red[co] + red[64 + co]) + (red[128 + co] + red[192 + co]);
    float m = __fdiv_rn(tot, 784.0f);
    out[nn * 64 + co] = m;
    slot_max_update(slot_out, m);
  }
}

// quant(mean) -> fc1 -> relu -> quant -> fc2, one 256-thread block.
__global__ void tail_kernel(const float* __restrict__ pooled,
                            const float* __restrict__ fw1, const float* __restrict__ fb1,
                            const float* __restrict__ fw2, const float* __restrict__ fb2,
                            const float* __restrict__ slot_in, float* __restrict__ out) {
  __shared__ float xq[1024];
  __shared__ float hq[256];
  __shared__ float s2s;
  const int t = threadIdx.x;
  const float s = p2_scale_f(slot_in[0], 255.0f);
  const float inv = __fdiv_rn(1.0f, s);
  for (int i = t; i < 1024; i += 256)
    xq[i] = __fmul_rn(rintf(__fmul_rn(pooled[i], inv)), s);
  __syncthreads();
  const int n = t >> 4, j = t & 15;
  float acc = 0.f;
  #pragma unroll 8
  for (int k = 0; k < 64; k++) acc += xq[n * 64 + k] * fw1[k * 16 + j];  // exact
  float z = fmaxf(__fadd_rn(acc, fb1[j]), 0.f);
  float bm = block_reduce_max256(z);
  if (t == 0) s2s = p2_scale_f(bm, 255.0f);
  __syncthreads();
  const float s2 = s2s, inv2 = __fdiv_rn(1.0f, s2);
  hq[t] = __fmul_rn(rintf(__fmul_rn(z, inv2)), s2);
  __syncthreads();
  if (t < 160) {
    const int n2 = t / 10, j2 = t % 10;
    float a2 = 0.f;
    #pragma unroll
    for (int k = 0; k < 16; k++) a2 += hq[n2 * 16 + k] * fw2[k * 10 + j2];  // exact
    out[t] = __fadd_rn(a2, fb2[j2]);
  }
}

extern "C" void kernel_launch(void* const* d_in, const int* in_sizes, int n_in,
                              void* d_out, int out_size, void* d_ws, size_t ws_size,
                              hipStream_t stream) {
  static const int h_ci[NL] = {3, 32, 16, 16, 32, 32, 64, 32, 64, 32, 64, 32};
  static const int h_co[NL] = {32, 16, 16, 32, 32, 64, 32, 64, 32, 64, 32, 64};
  static const int h_kk[NL] = {9, 9, 1, 9, 1, 9, 1, 9, 1, 9, 1, 9};
  static const int h_kp[NL] = {64, 288, 32, 160, 32, 288, 64, 288, 64, 288, 64, 288};

  float* ws = (float*)d_ws;
  float* slots = ws;                 // [0..13] activation-max slots
  float* wslot = ws + 16;            // [0..11] conv weight scales
  size_t off = 32;

  ushort* wq[NL];
  for (int l = 0; l < NL; l++) {
    wq[l] = (ushort*)(ws + off);
    off += (size_t)(h_co[l] * h_kp[l]) / 2;   // shorts -> float units
  }
  float* sgq[NL]; float* sbq[NL];
  for (int l = 0; l < NL; l++) { sgq[l] = ws + off; off += 64; }
  for (int l = 0; l < NL; l++) { sbq[l] = ws + off; off += 64; }
  float* fw1q = ws + off; off += 1024;
  float* fb1q = ws + off; off += 16;
  float* fw2q = ws + off; off += 160;
  float* fb2q = ws + off; off += 16;
  float* rawA = ws + off; off += 6422528;            // max: conv1 out 25.7 MB
  float* rawB = ws + off; off += 1605632;            // max: conv32 out 6.4 MB
  ushort4* xc = (ushort4*)(ws + off); off += 1605632; // 802816 pixels * 8 B
  float* P = ws + off; off += 1024;                  // pooled means [16][64]

  PrepArgs pa;
  for (int l = 0; l < NL; l++) {
    pa.in[l] = (const float*)d_in[1 + 3 * l]; pa.out[l] = (void*)wq[l];
    pa.n[l] = h_co[l] * h_ci[l] * h_kk[l];
    pa.mode[l] = (l == 0) ? 3 : 2; pa.tc[l] = 0;
    pa.ci[l] = h_ci[l]; pa.kk[l] = h_kk[l]; pa.kp[l] = h_kp[l]; pa.co[l] = h_co[l];
    pa.in[12 + l] = (const float*)d_in[2 + 3 * l]; pa.out[12 + l] = (void*)sgq[l];
    pa.n[12 + l] = h_co[l]; pa.mode[12 + l] = 0; pa.tc[12 + l] = 0;
    pa.ci[12 + l] = pa.kk[12 + l] = pa.kp[12 + l] = pa.co[12 + l] = 0;
    pa.in[24 + l] = (const float*)d_in[3 + 3 * l]; pa.out[24 + l] = (void*)sbq[l];
    pa.n[24 + l] = h_co[l]; pa.mode[24 + l] = 0; pa.tc[24 + l] = 0;
    pa.ci[24 + l] = pa.kk[24 + l] = pa.kp[24 + l] = pa.co[24 + l] = 0;
  }
  pa.in[36] = (const float*)d_in[37]; pa.out[36] = (void*)fw1q;
  pa.n[36] = 1024; pa.mode[36] = 1; pa.tc[36] = 16;
  pa.ci[36] = pa.kk[36] = pa.kp[36] = pa.co[36] = 0;
  pa.in[37] = (const float*)d_in[38]; pa.out[37] = (void*)fb1q;
  pa.n[37] = 16; pa.mode[37] = 0; pa.tc[37] = 0;
  pa.ci[37] = pa.kk[37] = pa.kp[37] = pa.co[37] = 0;
  pa.in[38] = (const float*)d_in[39]; pa.out[38] = (void*)fw2q;
  pa.n[38] = 160; pa.mode[38] = 1; pa.tc[38] = 10;
  pa.ci[38] = pa.kk[38] = pa.kp[38] = pa.co[38] = 0;
  pa.in[39] = (const float*)d_in[40]; pa.out[39] = (void*)fb2q;
  pa.n[39] = 10; pa.mode[39] = 0; pa.tc[39] = 0;
  pa.ci[39] = pa.kk[39] = pa.kp[39] = pa.co[39] = 0;

  const float* x = (const float*)d_in[0];
  const int nx4 = 16 * 3 * 224 * 224 / 4;   // 602112

  hipMemsetAsync(slots, 0, 32 * sizeof(float), stream);
  prep_kernel<<<168, 256, 0, stream>>>(pa, wslot, (const float4*)x, nx4, slots + 0);
  pack_x_kernel<<<784, 256, 0, stream>>>(x, xc, slots + 0);

  conv1_mfma<<<12544, 256, 0, stream>>>((const uint2*)xc, wq[0], sgq[0], sbq[0],
                                        rawA, slots + 0, wslot + 0, slots + 1);
  conv_mfma<32, 112, 16, true, true, 1><<<3136, 256, 0, stream>>>(
      rawA, wq[1], sgq[1], sbq[1], rawB, slots + 1, wslot + 1, slots + 2);
  conv_mfma<16, 56, 16, false, false, 1><<<784, 256, 0, stream>>>(
      rawB, wq[2], sgq[2], sbq[2], rawA, slots + 2, wslot + 2, slots + 3);
  conv_mfma<16, 56, 32, true, false, 1><<<784, 256, 0, stream>>>(
      rawA, wq[3], sgq[3], sbq[3], rawB, slots + 3, wslot + 3, slots + 4);
  conv_mfma<32, 56, 32, false, false, 1><<<784, 256, 0, stream>>>(
      rawB, wq[4], sgq[4], sbq[4], rawA, slots + 4, wslot + 4, slots + 5);
  conv_mfma<32, 56, 64, true, true, 1><<<784, 256, 0, stream>>>(
      rawA, wq[5], sgq[5], sbq[5], rawB, slots + 5, wslot + 5, slots + 6);
  conv_mfma<64, 28, 32, false, false, 2><<<392, 256, 0, stream>>>(
      rawB, wq[6], sgq[6], sbq[6], rawA, slots + 6, wslot + 6, slots + 7);
  conv_mfma<32, 28, 64, true, false, 4><<<784, 256, 0, stream>>>(
      rawA, wq[7], sgq[7], sbq[7], rawB, slots + 7, wslot + 7, slots + 8);
  conv_mfma<64, 28, 32, false, false, 2><<<392, 256, 0, stream>>>(
      rawB, wq[8], sgq[8], sbq[8], rawA, slots + 8, wslot + 8, slots + 9);
  conv_mfma<32, 28, 64, true, false, 4><<<784, 256, 0, stream>>>(
      rawA, wq[9], sgq[9], sbq[9], rawB, slots + 9, wslot + 9, slots + 10);
  conv_mfma<64, 28, 32, false, false, 2><<<392, 256, 0, stream>>>(
      rawB, wq[10], sgq[10], sbq[10], rawA, slots + 10, wslot + 10, slots + 11);
  conv_mfma<32, 28, 64, true, false, 4><<<784, 256, 0, stream>>>(
      rawA, wq[11], sgq[11], sbq[11], rawB, slots + 11, wslot + 11, slots + 12);

  avgpool_kernel<<<16, 256, 0, stream>>>(rawB, P, slots + 12, slots + 13);
  tail_kernel<<<1, 256, 0, stream>>>(P, fw1q, fb1q, fw2q, fb2q, slots + 13,
                                     (float*)d_out);
}